// Round 1
// baseline (357.021 us; speedup 1.0000x reference)
//
#include <hip/hip_runtime.h>
#include <stdint.h>

// conv2d 3x3 stride1 pad1, NCHW fp32, N=16 C=64 K=64 H=W=224
// Implicit GEMM on bf16 MFMA 32x32x16: M=outch, N=spatial(w), K=576 (tap-major).
// Grid: 16 n * 7 w-slabs(32 wide) * 8 h-chunks(28 rows) = 896 blocks x 128 thr (2 waves).
// Weights: 36 A-frags per lane held in VGPRs (loaded once per block).
// Input: fp32->bf16 into rolling 3-row LDS ring [3][34][64] with XOR swizzle.

#define HH 224
#define WW 224

typedef short bf16x8 __attribute__((ext_vector_type(8)));
typedef float f32x16 __attribute__((ext_vector_type(16)));

__device__ __forceinline__ unsigned short f2bf(float f) {
    union { float f; unsigned int u; } v; v.f = f;
    unsigned int u = v.u;
    return (unsigned short)((u + 0x7fffu + ((u >> 16) & 1u)) >> 16);  // RNE
}

__global__ __launch_bounds__(128, 2)
void conv3x3_mfma(const float* __restrict__ x, const float* __restrict__ wgt,
                  float* __restrict__ out) {
    // bf16 input tile: 3 row-slots x 34 w x 64 c, XOR-swizzled
    __shared__ __align__(16) unsigned short lds[3 * 34 * 64];

    const int tid  = threadIdx.x;
    const int lane = tid & 63;
    const int wv   = tid >> 6;     // wave id: outch half 0/1
    const int s    = lane & 31;    // A: outch-within-half, B: spatial w, C: col
    const int g    = lane >> 5;    // k-group (0/1): k = g*8 + j within a K-step

    const int bid = blockIdx.x;
    const int n   = bid / 56;
    const int rem = bid % 56;
    const int ws  = rem / 8;
    const int hc  = rem % 8;
    const int wbase = ws * 32;
    const int h0    = hc * 28;

    // ---- weight prologue: 36 K-step A-fragments in registers ----
    // k = ks*16 + g*8 + j ; tap = k>>6 ; c = k&63
    const int oc = wv * 32 + s;
    bf16x8 wfrag[36];
#pragma unroll
    for (int ks = 0; ks < 36; ++ks) {
        const int tap = ks >> 2;
        const int c0  = (ks & 3) * 16 + g * 8;
        bf16x8 f;
#pragma unroll
        for (int j = 0; j < 8; ++j)
            f[j] = (short)f2bf(wgt[(oc * 64 + c0 + j) * 9 + tap]);
        wfrag[ks] = f;
    }

    // ---- input row staging: fp32 global -> bf16 LDS (swizzled) ----
    auto stage = [&](int r, int slot) {
        // 34*64 = 2176 elems, 17 iters exactly at 128 threads; w fastest => coalesced
        for (int i = tid; i < 34 * 64; i += 128) {
            const int w = i % 34;
            const int c = i / 34;
            float v = 0.f;
            const int gw = wbase - 1 + w;
            if (r >= 0 && r < HH && gw >= 0 && gw < WW)
                v = x[((n * 64 + c) * HH + r) * WW + gw];
            const int byte = ((((slot * 34 + w) * 64 + c) * 2)) ^ ((w & 7) << 4);
            *(unsigned short*)((char*)lds + byte) = f2bf(v);
        }
    };

    stage(h0 - 1, (h0 + 2) % 3);
    stage(h0,      h0 % 3);

    for (int h = h0; h < h0 + 28; ++h) {
        stage(h + 1, (h + 1) % 3);   // rows >223 stage zeros
        __syncthreads();

        const int sl0 = (h + 2) % 3;  // input row h-1
        const int sl1 =  h      % 3;  // input row h
        const int sl2 = (h + 1) % 3;  // input row h+1

        f32x16 acc0 = {};
        f32x16 acc1 = {};
#pragma unroll
        for (int ks = 0; ks < 36; ++ks) {
            const int tap = ks >> 2;
            const int dh  = tap / 3;
            const int dw  = tap % 3;
            const int slot = (dh == 0) ? sl0 : ((dh == 1) ? sl1 : sl2);
            const int c0  = (ks & 3) * 16 + g * 8;
            const int wl  = s + dw;  // LDS w index (0 == global w wbase-1)
            const int byte = ((((slot * 34 + wl) * 64 + c0) * 2)) ^ ((wl & 7) << 4);
            bf16x8 b = *(const bf16x8*)((const char*)lds + byte);
            if (ks & 1)
                acc1 = __builtin_amdgcn_mfma_f32_32x32x16_bf16(wfrag[ks], b, acc1, 0, 0, 0);
            else
                acc0 = __builtin_amdgcn_mfma_f32_32x32x16_bf16(wfrag[ks], b, acc0, 0, 0, 0);
        }
        const f32x16 acc = acc0 + acc1;

        // C layout: col = lane&31 = spatial w, row = (reg&3) + 8*(reg>>2) + 4*g = outch
#pragma unroll
        for (int rg = 0; rg < 16; ++rg) {
            const int oco = wv * 32 + (rg & 3) + 8 * (rg >> 2) + 4 * g;
            out[((n * 64 + oco) * HH + h) * WW + wbase + s] = acc[rg];
        }
        __syncthreads();
    }
}

extern "C" void kernel_launch(void* const* d_in, const int* in_sizes, int n_in,
                              void* d_out, int out_size, void* d_ws, size_t ws_size,
                              hipStream_t stream) {
    const float* x   = (const float*)d_in[0];
    const float* wgt = (const float*)d_in[1];
    float* out       = (float*)d_out;
    conv3x3_mfma<<<dim3(16 * 7 * 8), dim3(128), 0, stream>>>(x, wgt, out);
}

// Round 2
// 201.454 us; speedup vs baseline: 1.7722x; 1.7722x over previous
//
#include <hip/hip_runtime.h>

// conv2d 3x3 stride1 pad1, NCHW fp32, N=16 C=K=64 H=W=224
// Implicit GEMM on bf16 MFMA 32x32x16. M=outch(64), N=w(32), K=576 tap-major.
// Block: 256 thr = 4 waves (2 oc-halves x 2 row-parities), 2 output rows/iter.
// Input: 6-slot LDS row ring [34 w][64 c] bf16, XOR swizzle ((w&7)<<4) on byte.
// T14 pipeline: global->reg loads for rows h+3,h+4 issued BEFORE compute of
// rows h,h+1; cvt + ds_write_b128 after the barrier. Weights in VGPRs (144).

#define HH 224
#define WW 224
#define CHW (HH * WW)
#define PLANE 4352  // 34 * 128 bytes per row-slot

typedef short bf16x8 __attribute__((ext_vector_type(8)));
typedef float f32x16 __attribute__((ext_vector_type(16)));

__device__ __forceinline__ unsigned short f2bf(float f) {
    union { float f; unsigned int u; } v; v.f = f;
    unsigned int u = v.u;
    return (unsigned short)((u + 0x7fffu + ((u >> 16) & 1u)) >> 16);  // RNE
}

__global__ __launch_bounds__(256, 2)
void conv3x3_mfma(const float* __restrict__ x, const float* __restrict__ wgt,
                  float* __restrict__ out) {
    __shared__ __align__(16) unsigned short lds[6 * 34 * 64];

    const int tid  = threadIdx.x;
    const int lane = tid & 63;
    const int wv   = tid >> 6;
    const int och  = wv & 1;   // oc half (0/1)
    const int rp   = wv >> 1;  // row parity (0/1)
    const int s    = lane & 31;
    const int g    = lane >> 5;

    const int bid = blockIdx.x;
    const int n   = bid / 56;
    const int rem = bid % 56;
    const int ws  = rem / 8;
    const int hc  = rem % 8;
    const int wbase = ws * 32;
    const int h0    = hc * 28;

    // ---- prologue: stage input rows h0-1 .. h0+2 into ring ----
    for (int p = tid; p < 4 * 272; p += 256) {
        const int rrel = p / 272;
        const int q    = p % 272;
        const int c8   = q / 34;
        const int wl   = q % 34;
        const int r    = h0 - 1 + rrel;
        const int gw   = wbase - 1 + wl;
        bf16x8 f = {};
        if (r >= 0 && r < HH && gw >= 0 && gw < WW) {
            const float* px = x + (n * 64 + c8 * 8) * CHW + r * WW + gw;
#pragma unroll
            for (int j = 0; j < 8; ++j)
                f[j] = (short)f2bf(px[j * CHW]);
        }
        const int byte = ((r + 6) % 6) * PLANE + wl * 128 + ((c8 * 16) ^ ((wl & 7) << 4));
        *(bf16x8*)((char*)lds + byte) = f;
    }

    // ---- weights: 36 K-step A-fragments in registers ----
    const int oc = och * 32 + s;
    bf16x8 wfrag[36];
#pragma unroll
    for (int ks = 0; ks < 36; ++ks) {
        const int tap = ks >> 2;
        const int c0  = (ks & 3) * 16 + g * 8;
        bf16x8 f;
#pragma unroll
        for (int j = 0; j < 8; ++j)
            f[j] = (short)f2bf(wgt[(oc * 64 + c0 + j) * 9 + tap]);
        wfrag[ks] = f;
    }
    __syncthreads();

    // per-thread staging coords: main part covers p=tid (c8=tid/34, wl=tid%34);
    // tail p=256+tid for tid<16 covers (c8=7, wl=18+tid)
    const int c8A = tid / 34, wlA = tid % 34;
    const int c8B = 7,        wlB = 18 + tid;

    for (int it = 0; it < 14; ++it) {
        const int h = h0 + 2 * it;

        // ---- issue prefetch loads for rows h+3, h+4 (consumed after barrier) ----
        float pA0[8], pA1[8], pB0[8], pB1[8];
        if (it < 13) {
            const int r0 = h + 3, r1 = h + 4;
            {
                const int gwA = wbase - 1 + wlA;
                const bool okw = (gwA >= 0 && gwA < WW);
                const bool ok0 = okw && (r0 < HH);
                const bool ok1 = okw && (r1 < HH);
                const float* px = x + (n * 64 + c8A * 8) * CHW + gwA;
#pragma unroll
                for (int j = 0; j < 8; ++j) pA0[j] = ok0 ? px[j * CHW + r0 * WW] : 0.f;
#pragma unroll
                for (int j = 0; j < 8; ++j) pA1[j] = ok1 ? px[j * CHW + r1 * WW] : 0.f;
            }
            if (tid < 16) {
                const int gwB = wbase - 1 + wlB;
                const bool okw = (gwB >= 0 && gwB < WW);
                const bool ok0 = okw && (r0 < HH);
                const bool ok1 = okw && (r1 < HH);
                const float* px = x + (n * 64 + c8B * 8) * CHW + gwB;
#pragma unroll
                for (int j = 0; j < 8; ++j) pB0[j] = ok0 ? px[j * CHW + r0 * WW] : 0.f;
#pragma unroll
                for (int j = 0; j < 8; ++j) pB1[j] = ok1 ? px[j * CHW + r1 * WW] : 0.f;
            }
        }

        // ---- compute output row hr = h + rp from ring rows hr-1..hr+1 ----
        const int hr  = h + rp;
        const int slB[3] = { ((hr + 5) % 6) * PLANE,
                             ((hr + 6) % 6) * PLANE,
                             ((hr + 7) % 6) * PLANE };

        f32x16 acc0 = {}, acc1 = {};
#pragma unroll
        for (int ks = 0; ks < 36; ++ks) {
            const int tap = ks >> 2;
            const int dh  = tap / 3;
            const int dw  = tap % 3;
            const int cq  = ks & 3;
            const int wl  = s + dw;
            const int byte = slB[dh] + wl * 128 + ((cq * 32 + g * 16) ^ ((wl & 7) << 4));
            const bf16x8 b = *(const bf16x8*)((const char*)lds + byte);
            if (ks & 1)
                acc1 = __builtin_amdgcn_mfma_f32_32x32x16_bf16(wfrag[ks], b, acc1, 0, 0, 0);
            else
                acc0 = __builtin_amdgcn_mfma_f32_32x32x16_bf16(wfrag[ks], b, acc0, 0, 0, 0);
        }

        // ---- C store: col = s (w), row = (rg&3)+8*(rg>>2)+4*g (oc) ----
        {
            const f32x16 a = acc0 + acc1;
            float* po = out + (n * 64 + och * 32 + 4 * g) * CHW + hr * WW + wbase + s;
#pragma unroll
            for (int rg = 0; rg < 16; ++rg) {
                const int oco = (rg & 3) + 8 * (rg >> 2);
                po[oco * CHW] = a[rg];
            }
        }

        __syncthreads();  // all reads of evicted slots done

        // ---- cvt + LDS write of prefetched rows ----
        if (it < 13) {
            const int s0 = ((h + 3) % 6) * PLANE;
            const int s1 = ((h + 4) % 6) * PLANE;
            {
                bf16x8 f0, f1;
#pragma unroll
                for (int j = 0; j < 8; ++j) {
                    f0[j] = (short)f2bf(pA0[j]);
                    f1[j] = (short)f2bf(pA1[j]);
                }
                const int lo = wlA * 128 + ((c8A * 16) ^ ((wlA & 7) << 4));
                *(bf16x8*)((char*)lds + s0 + lo) = f0;
                *(bf16x8*)((char*)lds + s1 + lo) = f1;
            }
            if (tid < 16) {
                bf16x8 f0, f1;
#pragma unroll
                for (int j = 0; j < 8; ++j) {
                    f0[j] = (short)f2bf(pB0[j]);
                    f1[j] = (short)f2bf(pB1[j]);
                }
                const int lo = wlB * 128 + ((c8B * 16) ^ ((wlB & 7) << 4));
                *(bf16x8*)((char*)lds + s0 + lo) = f0;
                *(bf16x8*)((char*)lds + s1 + lo) = f1;
            }
        }
        __syncthreads();  // new rows visible before next iter's reads
    }
}

extern "C" void kernel_launch(void* const* d_in, const int* in_sizes, int n_in,
                              void* d_out, int out_size, void* d_ws, size_t ws_size,
                              hipStream_t stream) {
    const float* x   = (const float*)d_in[0];
    const float* wgt = (const float*)d_in[1];
    float* out       = (float*)d_out;
    conv3x3_mfma<<<dim3(16 * 7 * 8), dim3(256), 0, stream>>>(x, wgt, out);
}

// Round 3
// 190.724 us; speedup vs baseline: 1.8719x; 1.0563x over previous
//
#include <hip/hip_runtime.h>

// conv2d 3x3 stride1 pad1, NCHW fp32, N=16 C=K=64 H=W=224
// Implicit GEMM, bf16 MFMA 32x32x16. Block 256 thr = 4 waves (2 oc x 2 rowpair).
// Each wave: 2 output rows/iter with B-frag reuse across dh (48 reads, 72 MFMA).
// 12-slot LDS row ring, XOR swizzle, ONE barrier per 4-row iter.
// Staging: rotating 8-reg row batches issued between dw-sections (T14 split).
// T19 sched_group_barrier pins DS_READ:4/MFMA:6 interleave (caps reg pressure).

#define HH 224
#define WW 224
#define CHW (HH * WW)
#define PLANE 4352       // 34 w * 64 c * 2 B per row-slot
#define NSLOT 12

typedef short bf16x8 __attribute__((ext_vector_type(8)));
typedef float f32x16 __attribute__((ext_vector_type(16)));

__device__ __forceinline__ unsigned short f2bf(float f) {
    union { float f; unsigned int u; } v; v.f = f;
    unsigned int u = v.u;
    return (unsigned short)((u + 0x7fffu + ((u >> 16) & 1u)) >> 16);  // RNE
}

#define SGB __builtin_amdgcn_sched_group_barrier

// per (dw): for cq 0..3: 4 ds_read_b128 + 6 MFMA (2 rows x 3 dh), static wfrag idx
#define MMA_DW(dw) do {                                                          \
    const int wl_  = s + (dw);                                                   \
    const int cob_ = wl_ * 128;                                                  \
    const int swz_ = (wl_ & 7) << 4;                                             \
    _Pragma("unroll")                                                            \
    for (int cq = 0; cq < 4; ++cq) {                                             \
        const int off_ = cob_ + ((cq * 32 + g * 16) ^ swz_);                     \
        const bf16x8 b0 = *(const bf16x8*)((const char*)lds + sl0 + off_);       \
        const bf16x8 b1 = *(const bf16x8*)((const char*)lds + sl1 + off_);       \
        const bf16x8 b2 = *(const bf16x8*)((const char*)lds + sl2 + off_);       \
        const bf16x8 b3 = *(const bf16x8*)((const char*)lds + sl3 + off_);       \
        a0 = __builtin_amdgcn_mfma_f32_32x32x16_bf16(wfrag[(0 + (dw)) * 4 + cq], b0, a0, 0, 0, 0); \
        a1 = __builtin_amdgcn_mfma_f32_32x32x16_bf16(wfrag[(0 + (dw)) * 4 + cq], b1, a1, 0, 0, 0); \
        a0 = __builtin_amdgcn_mfma_f32_32x32x16_bf16(wfrag[(3 + (dw)) * 4 + cq], b1, a0, 0, 0, 0); \
        a1 = __builtin_amdgcn_mfma_f32_32x32x16_bf16(wfrag[(3 + (dw)) * 4 + cq], b2, a1, 0, 0, 0); \
        a0 = __builtin_amdgcn_mfma_f32_32x32x16_bf16(wfrag[(6 + (dw)) * 4 + cq], b2, a0, 0, 0, 0); \
        a1 = __builtin_amdgcn_mfma_f32_32x32x16_bf16(wfrag[(6 + (dw)) * 4 + cq], b3, a1, 0, 0, 0); \
        SGB(0x100, 4, 0);                                                        \
        SGB(0x008, 6, 0);                                                        \
    }                                                                            \
} while (0)

#define LOADROW(r, pv) do {                                                      \
    _Pragma("unroll")                                                            \
    for (int j = 0; j < 8; ++j) (pv)[j] = ((r) < HH) ? pxm[j * CHW + (r) * WW] : 0.f; \
} while (0)

#define CVT_WRITE(r, pv) do {                                                    \
    bf16x8 f_;                                                                   \
    _Pragma("unroll")                                                            \
    for (int j = 0; j < 8; ++j) f_[j] = (short)f2bf((pv)[j]);                    \
    *(bf16x8*)((char*)lds + ((r) % NSLOT) * PLANE + lom) = f_;                   \
} while (0)

__global__ __launch_bounds__(256, 2)
void conv3x3_mfma(const float* __restrict__ x, const float* __restrict__ wgt,
                  float* __restrict__ out) {
    __shared__ __align__(16) unsigned short lds[NSLOT * 34 * 64];

    const int tid  = threadIdx.x;
    const int lane = tid & 63;
    const int wv   = tid >> 6;
    const int och  = wv & 1;   // oc half
    const int rp   = wv >> 1;  // row-pair (0: rows h,h+1 ; 1: rows h+2,h+3)
    const int s    = lane & 31;
    const int g    = lane >> 5;

    const int bid = blockIdx.x;
    const int n   = bid / 56;
    const int rem = bid % 56;
    const int ws  = rem / 8;
    const int hc  = rem % 8;
    const int wbase = ws * 32;
    const int h0    = hc * 28;

    // ---- prologue: stage rows h0-1 .. h0+4 ----
    for (int p = tid; p < 6 * 272; p += 256) {
        const int rrel = p / 272;
        const int q = p % 272;
        const int c8 = q / 34;
        const int wl = q % 34;
        const int r  = h0 - 1 + rrel;
        const int gw = wbase - 1 + wl;
        bf16x8 f = {};
        if (r >= 0 && r < HH && gw >= 0 && gw < WW) {
            const float* px = x + (n * 64 + c8 * 8) * CHW + r * WW + gw;
#pragma unroll
            for (int j = 0; j < 8; ++j) f[j] = (short)f2bf(px[j * CHW]);
        }
        *(bf16x8*)((char*)lds + ((r + NSLOT) % NSLOT) * PLANE + wl * 128
                   + ((c8 * 16) ^ ((wl & 7) << 4))) = f;
    }

    // ---- weights: 36 A-frags (tap-major K) ----
    const int oc = och * 32 + s;
    bf16x8 wfrag[36];
#pragma unroll
    for (int ks = 0; ks < 36; ++ks) {
        const int tap = ks >> 2;
        const int c0  = (ks & 3) * 16 + g * 8;
        bf16x8 f;
#pragma unroll
        for (int j = 0; j < 8; ++j) f[j] = (short)f2bf(wgt[(oc * 64 + c0 + j) * 9 + tap]);
        wfrag[ks] = f;
    }
    __syncthreads();

    // ---- staging coords ----
    // main: thread owns (c8m, interior w); gw always in-bounds
    const int c8m = tid >> 5;
    const int wlm = 1 + (tid & 31);
    const float* pxm = x + (n * 64 + c8m * 8) * CHW + (wbase + (tid & 31));
    const int lom = wlm * 128 + ((c8m * 16) ^ ((wlm & 7) << 4));
    // halo: lanes<16 of wave wv handle row h+5+wv, w edges
    const bool hth = lane < 16;
    const int c8h = (lane >> 1) & 7;
    const int wlh = (lane & 1) * 33;
    const int gwh = wbase - 1 + wlh;
    const bool hokw = (gwh >= 0 && gwh < WW);
    const float* pxh = x + (n * 64 + c8h * 8) * CHW + gwh;
    const int loh = wlh * 128 + ((c8h * 16) ^ ((wlh & 7) << 4));

    for (int it = 0; it < 7; ++it) {
        const int h  = h0 + 4 * it;
        const bool st = (it < 6);
        const int base = h + 2 * rp;
        const int sl0 = ((base - 1 + NSLOT) % NSLOT) * PLANE;
        const int sl1 = (( base      ) % NSLOT) * PLANE;
        const int sl2 = ((base + 1) % NSLOT) * PLANE;
        const int sl3 = ((base + 2) % NSLOT) * PLANE;

        float pv0[8], pv1[8], hv[8];
        if (st) {
            LOADROW(h + 5, pv0);
            if (hth) {
                const int rh = h + 5 + wv;
                const bool ok = hokw && (rh < HH);
#pragma unroll
                for (int j = 0; j < 8; ++j) hv[j] = ok ? pxh[j * CHW + rh * WW] : 0.f;
            }
        }

        f32x16 a0 = {}, a1 = {};
        MMA_DW(0);

        if (st) {
            CVT_WRITE(h + 5, pv0);
            if (hth) {
                bf16x8 f_;
#pragma unroll
                for (int j = 0; j < 8; ++j) f_[j] = (short)f2bf(hv[j]);
                *(bf16x8*)((char*)lds + ((h + 5 + wv) % NSLOT) * PLANE + loh) = f_;
            }
            LOADROW(h + 6, pv1);
        }

        MMA_DW(1);

        if (st) {
            CVT_WRITE(h + 6, pv1);
            LOADROW(h + 7, pv0);
        }

        MMA_DW(2);

        if (st) {
            CVT_WRITE(h + 7, pv0);
            LOADROW(h + 8, pv1);
        }

        // ---- C stores: rows base, base+1 ----
        {
            float* po = out + (n * 64 + och * 32 + 4 * g) * CHW + base * WW + wbase + s;
#pragma unroll
            for (int rg = 0; rg < 16; ++rg) {
                const int oco = ((rg & 3) + 8 * (rg >> 2)) * CHW;
                po[oco]      = a0[rg];
                po[oco + WW] = a1[rg];
            }
        }

        if (st) CVT_WRITE(h + 8, pv1);

        __syncthreads();  // writes h+5..h+8 visible; next iter reads h+3..h+8
    }
}

extern "C" void kernel_launch(void* const* d_in, const int* in_sizes, int n_in,
                              void* d_out, int out_size, void* d_ws, size_t ws_size,
                              hipStream_t stream) {
    const float* x   = (const float*)d_in[0];
    const float* wgt = (const float*)d_in[1];
    float* out       = (float*)d_out;
    conv3x3_mfma<<<dim3(16 * 7 * 8), dim3(256), 0, stream>>>(x, wgt, out);
}

// Round 4
// 177.133 us; speedup vs baseline: 2.0156x; 1.0767x over previous
//
#include <hip/hip_runtime.h>

// conv2d 3x3 s1 p1, NCHW fp32, N=16 C=K=64 H=W=224. Implicit GEMM bf16 MFMA 32x32x16.
// Kernel 1 (wprep): wgt fp32 [64][64][3][3] -> bf16 K-major [36 ks][2 g][64 oc][8 c] in d_ws.
// Kernel 2 (conv): 448 blocks x 256 thr (4 waves = 2 oc-halves x 2 row-groups), R=4 rows/wave,
//   8 output rows/block-iter, 7 iters over a 56-row chunk. 18-slot LDS row ring (76.5 KB,
//   2 blocks/CU). Weights dh0/dh1 in 96 VGPRs; dh2 streamed from L2 (ping-pong, 16 regs).
//   8 staging batches per iter interleaved with 6 MMA sections + 2 store halves; 1 barrier/iter.

#define HH 224
#define WW 224
#define CHW (HH * WW)
#define PLANE 4352      // 34 w * 64 c * 2 B
#define NSLOT 18

typedef short bf16x8 __attribute__((ext_vector_type(8)));
typedef float f32x16 __attribute__((ext_vector_type(16)));

__device__ __forceinline__ unsigned short f2bf(float f) {
    union { float f; unsigned int u; } v; v.f = f;
    unsigned int u = v.u;
    return (unsigned short)((u + 0x7fffu + ((u >> 16) & 1u)) >> 16);  // RNE
}

#define SGB  __builtin_amdgcn_sched_group_barrier
#define MFMA __builtin_amdgcn_mfma_f32_32x32x16_bf16

__global__ void wprep_kernel(const float* __restrict__ wgt, unsigned short* __restrict__ wb) {
    const int i = blockIdx.x * 256 + threadIdx.x;
    if (i >= 36864) return;
    const int j   = i & 7;
    const int oc  = (i >> 3) & 63;
    const int g   = (i >> 9) & 1;
    const int ks  = i >> 10;
    const int tap = ks >> 2;
    const int c   = (ks & 3) * 16 + g * 8 + j;
    wb[i] = f2bf(wgt[(oc * 64 + c) * 9 + tap]);
}

// 6 ds_read_b128 + 12 MFMA (4 rows x 3 dh) for one (dw, cq); all indices literal.
#define MMA_CQ(dw, cq, WFU) do {                                              \
    const int off_ = (((cq) * 32 + g16) ^ swz_);                              \
    const bf16x8 B0 = *(const bf16x8*)(ldsB + sl0 + wb_ + off_);              \
    const bf16x8 B1 = *(const bf16x8*)(ldsB + sl1 + wb_ + off_);              \
    const bf16x8 B2 = *(const bf16x8*)(ldsB + sl2 + wb_ + off_);              \
    const bf16x8 B3 = *(const bf16x8*)(ldsB + sl3 + wb_ + off_);              \
    const bf16x8 B4 = *(const bf16x8*)(ldsB + sl4 + wb_ + off_);              \
    const bf16x8 B5 = *(const bf16x8*)(ldsB + sl5 + wb_ + off_);              \
    a0 = MFMA(wfrag[(dw)*4 + (cq)], B0, a0, 0, 0, 0);                         \
    a1 = MFMA(wfrag[(dw)*4 + (cq)], B1, a1, 0, 0, 0);                         \
    a2 = MFMA(wfrag[(dw)*4 + (cq)], B2, a2, 0, 0, 0);                         \
    a3 = MFMA(wfrag[(dw)*4 + (cq)], B3, a3, 0, 0, 0);                         \
    a0 = MFMA(wfrag[12 + (dw)*4 + (cq)], B1, a0, 0, 0, 0);                    \
    a1 = MFMA(wfrag[12 + (dw)*4 + (cq)], B2, a1, 0, 0, 0);                    \
    a2 = MFMA(wfrag[12 + (dw)*4 + (cq)], B3, a2, 0, 0, 0);                    \
    a3 = MFMA(wfrag[12 + (dw)*4 + (cq)], B4, a3, 0, 0, 0);                    \
    a0 = MFMA(WFU, B2, a0, 0, 0, 0);                                          \
    a1 = MFMA(WFU, B3, a1, 0, 0, 0);                                          \
    a2 = MFMA(WFU, B4, a2, 0, 0, 0);                                          \
    a3 = MFMA(WFU, B5, a3, 0, 0, 0);                                          \
    SGB(0x100, 6, 0); SGB(0x008, 12, 0);                                      \
} while (0)

// One section = 2 cq of one dw; first issues next section's dh2 frags (ping-pong).
#define SECTION(dw, cqp, WFU0, WFU1, WFLD0, WFLD1, ldw, lcqp) do {            \
    WFLD0 = *(const bf16x8*)(wlane + ((6 + (ldw))*4 + 2*(lcqp)    ) * 1024);  \
    WFLD1 = *(const bf16x8*)(wlane + ((6 + (ldw))*4 + 2*(lcqp) + 1) * 1024);  \
    const int wl_  = s + (dw);                                                \
    const int swz_ = (wl_ & 7) << 4;                                          \
    const int wb_  = wl_ * 128;                                               \
    MMA_CQ(dw, 2*(cqp),     WFU0);                                            \
    MMA_CQ(dw, 2*(cqp) + 1, WFU1);                                            \
} while (0)

#define STI(k) do { if (st) {                                                 \
    const int r_ = h + 9 + (k);                                               \
    const bool ok_ = (r_ < HH);                                               \
    _Pragma("unroll")                                                         \
    for (int j = 0; j < 8; ++j) pv[j] = ok_ ? pxm[j*CHW + r_*WW] : 0.f;       \
    if (tid >= 240) {                                                         \
        const bool okh_ = ok_ && hokw;                                        \
        _Pragma("unroll")                                                     \
        for (int j = 0; j < 8; ++j) hv[j] = okh_ ? pxh[j*CHW + r_*WW] : 0.f;  \
    } } } while (0)

#define STW(k) do { if (st) {                                                 \
    int sw_ = slw + (k); if (sw_ >= NSLOT) sw_ -= NSLOT;                      \
    bf16x8 f_;                                                                \
    _Pragma("unroll")                                                         \
    for (int j = 0; j < 8; ++j) f_[j] = (short)f2bf(pv[j]);                   \
    *(bf16x8*)(ldsB + sw_ * PLANE + lom) = f_;                                \
    if (tid >= 240) {                                                         \
        bf16x8 fh_;                                                           \
        _Pragma("unroll")                                                     \
        for (int j = 0; j < 8; ++j) fh_[j] = (short)f2bf(hv[j]);              \
        *(bf16x8*)(ldsB + sw_ * PLANE + loh) = fh_;                           \
    } } } while (0)

__global__ __launch_bounds__(256, 2)
void conv3x3_mfma(const float* __restrict__ x, const unsigned short* __restrict__ wb,
                  float* __restrict__ out) {
    __shared__ __align__(16) unsigned short lds[NSLOT * 34 * 64];  // 78336 B
    char* ldsB = (char*)lds;

    const int tid  = threadIdx.x;
    const int lane = tid & 63;
    const int wv   = tid >> 6;
    const int och  = wv & 1;   // oc half
    const int rg4  = wv >> 1;  // row group (4 rows each)
    const int s    = lane & 31;
    const int g    = lane >> 5;
    const int g16  = g * 16;

    const int bid = blockIdx.x;
    const int n   = bid / 28;
    const int rem = bid % 28;
    const int ws  = rem / 4;
    const int hc  = rem % 4;
    const int wbase = ws * 32;
    const int h0    = hc * 56;

    // ---- weights: dh0/dh1 resident (24 frags), dh2 ping-pong buffers ----
    const unsigned short* wlane = wb + g * 512 + (och * 32 + s) * 8;
    bf16x8 wfrag[24];
#pragma unroll
    for (int ks = 0; ks < 24; ++ks)
        wfrag[ks] = *(const bf16x8*)(wlane + ks * 1024);
    bf16x8 wfA0 = *(const bf16x8*)(wlane + 24 * 1024);
    bf16x8 wfA1 = *(const bf16x8*)(wlane + 25 * 1024);
    bf16x8 wfB0 = {}, wfB1 = {};

    // ---- prologue: stage rows h0-1 .. h0+8 ----
    for (int p = tid; p < 10 * 272; p += 256) {
        const int rrel = p / 272;
        const int q  = p % 272;
        const int c8 = q / 34;
        const int wl = q % 34;
        const int r  = h0 - 1 + rrel;
        const int gw = wbase - 1 + wl;
        bf16x8 f = {};
        if (r >= 0 && r < HH && gw >= 0 && gw < WW) {
            const float* px = x + (n * 64 + c8 * 8) * CHW + r * WW + gw;
#pragma unroll
            for (int j = 0; j < 8; ++j) f[j] = (short)f2bf(px[j * CHW]);
        }
        *(bf16x8*)(ldsB + ((r + NSLOT) % NSLOT) * PLANE + wl * 128
                   + ((c8 * 16) ^ ((wl & 7) << 4))) = f;
    }

    // ---- staging coords ----
    const int c8m = tid >> 5;
    const int wlm = 1 + (tid & 31);
    const float* pxm = x + (n * 64 + c8m * 8) * CHW + (wbase + (tid & 31));
    const int lom = wlm * 128 + ((c8m * 16) ^ ((wlm & 7) << 4));
    // halo: tid 240..255 -> lane 48..63: c8 = lane&7, wl = 0 or 33
    const int c8h = lane & 7;
    const int wlh = ((lane >> 3) & 1) * 33;
    const int gwh = wbase - 1 + wlh;
    const bool hokw = (gwh >= 0 && gwh < WW);
    const float* pxh = x + (n * 64 + c8h * 8) * CHW + gwh;
    const int loh = wlh * 128 + ((c8h * 16) ^ ((wlh & 7) << 4));

    __syncthreads();

#pragma unroll 1
    for (int it = 0; it < 7; ++it) {
        const int h  = h0 + 8 * it;
        const int hb = h + 4 * rg4;
        const bool st = (it < 6);
        const int slw = (h + 9) % NSLOT;

        int t_ = (hb - 1 + NSLOT) % NSLOT;
        const int sl0 = t_ * PLANE; t_ = (t_ + 1 == NSLOT) ? 0 : t_ + 1;
        const int sl1 = t_ * PLANE; t_ = (t_ + 1 == NSLOT) ? 0 : t_ + 1;
        const int sl2 = t_ * PLANE; t_ = (t_ + 1 == NSLOT) ? 0 : t_ + 1;
        const int sl3 = t_ * PLANE; t_ = (t_ + 1 == NSLOT) ? 0 : t_ + 1;
        const int sl4 = t_ * PLANE; t_ = (t_ + 1 == NSLOT) ? 0 : t_ + 1;
        const int sl5 = t_ * PLANE;

        float pv[8], hv[8];
        f32x16 a0 = {}, a1 = {}, a2 = {}, a3 = {};

        STI(0); SECTION(0, 0, wfA0, wfA1, wfB0, wfB1, 0, 1); STW(0);
        STI(1); SECTION(0, 1, wfB0, wfB1, wfA0, wfA1, 1, 0); STW(1);
        STI(2); SECTION(1, 0, wfA0, wfA1, wfB0, wfB1, 1, 1); STW(2);
        STI(3); SECTION(1, 1, wfB0, wfB1, wfA0, wfA1, 2, 0); STW(3);
        STI(4); SECTION(2, 0, wfA0, wfA1, wfB0, wfB1, 2, 1); STW(4);
        STI(5); SECTION(2, 1, wfB0, wfB1, wfA0, wfA1, 0, 0); STW(5);

        // ---- C stores: rows hb..hb+3 (col = s = w; row = (rg&3)+8*(rg>>2)+4g = oc) ----
        float* po = out + (n * 64 + och * 32 + 4 * g) * CHW + hb * WW + wbase + s;
        STI(6);
#pragma unroll
        for (int rg = 0; rg < 16; ++rg) {
            const int o_ = ((rg & 3) + 8 * (rg >> 2)) * CHW;
            po[o_]      = a0[rg];
            po[o_ + WW] = a1[rg];
        }
        STW(6); STI(7);
#pragma unroll
        for (int rg = 0; rg < 16; ++rg) {
            const int o_ = ((rg & 3) + 8 * (rg >> 2)) * CHW;
            po[o_ + 2 * WW] = a2[rg];
            po[o_ + 3 * WW] = a3[rg];
        }
        STW(7);

        __syncthreads();  // rows h+9..h+16 visible for next iter
    }
}

extern "C" void kernel_launch(void* const* d_in, const int* in_sizes, int n_in,
                              void* d_out, int out_size, void* d_ws, size_t ws_size,
                              hipStream_t stream) {
    const float* x   = (const float*)d_in[0];
    const float* wgt = (const float*)d_in[1];
    float* out       = (float*)d_out;
    unsigned short* wbuf = (unsigned short*)d_ws;  // 73728 B needed

    wprep_kernel<<<dim3(144), dim3(256), 0, stream>>>(wgt, wbuf);
    conv3x3_mfma<<<dim3(448), dim3(256), 0, stream>>>(x, wbuf, out);
}